// Round 10
// baseline (253.343 us; speedup 1.0000x reference)
//
#include <hip/hip_runtime.h>
#include <hip/hip_bf16.h>

// Shapes (fixed): B=1, S=2048, HID=2048, NH=16, NKV=4, HD=128
// Inputs: fp32. Output: fp32. Internal compute: bf16 MFMA, fp32 accumulate.
typedef __bf16 bf16_t;
typedef __attribute__((ext_vector_type(8))) __bf16 bf16x8;
typedef __attribute__((ext_vector_type(4))) __bf16 bf16x4;
typedef __attribute__((ext_vector_type(4))) float f32x4;

#define S_LEN 2048
#define HID 2048
#define NH 16
#define NKV 4
#define HD 128

__device__ __forceinline__ void gll16(const bf16_t* g, bf16_t* l) {
    __builtin_amdgcn_global_load_lds(
        (const __attribute__((address_space(1))) unsigned int*)g,
        (__attribute__((address_space(3))) unsigned int*)l, 16, 0, 0);
}

__device__ __forceinline__ bf16x8 cvt2x4(float4 a, float4 b) {
    bf16x8 o;
    o[0]=(bf16_t)a.x; o[1]=(bf16_t)a.y; o[2]=(bf16_t)a.z; o[3]=(bf16_t)a.w;
    o[4]=(bf16_t)b.x; o[5]=(bf16_t)b.y; o[6]=(bf16_t)b.z; o[7]=(bf16_t)b.w;
    return o;
}

// ---------------------------------------------------------------------------
__global__ __launch_bounds__(256) void cvt_f32_bf16(const float* __restrict__ in,
                                                    bf16_t* __restrict__ out, int n)
{
    int i = (blockIdx.x * 256 + threadIdx.x) * 8;
    if (i >= n) return;
    float4 a = *(const float4*)&in[i];
    float4 b = *(const float4*)&in[i + 4];
    *(bf16x8*)&out[i] = cvt2x4(a, b);
}

// Fused weight conversion: [wq | wk | wv] fp32 -> contiguous bf16 (3072 x 2048)
__global__ __launch_bounds__(256) void cvt_w3(const float* __restrict__ wq,
                                              const float* __restrict__ wk,
                                              const float* __restrict__ wv,
                                              bf16_t* __restrict__ out)
{
    int i = (blockIdx.x * 256 + threadIdx.x) * 8;
    const float* src; int off;
    if (i < 4 * 1024 * 1024)      { src = wq; off = i; }
    else if (i < 5 * 1024 * 1024) { src = wk; off = i - 4 * 1024 * 1024; }
    else                          { src = wv; off = i - 5 * 1024 * 1024; }
    float4 a = *(const float4*)&src[off];
    float4 b = *(const float4*)&src[off + 4];
    *(bf16x8*)&out[i] = cvt2x4(a, b);
}

// ---------------------------------------------------------------------------
// m97-recipe NT GEMM (unchanged): 128x128 tile, BK=64, 32 MFMA/iter,
// gll width-16 staging, XOR-swizzled unpadded LDS.
// MODE 0: C fp32 row-major. MODE 1: qkv routing (C=q bf16 / Ck / Cvt^T).
// ---------------------------------------------------------------------------
template<int MODE, typename CT>
__global__ __launch_bounds__(256, 2) void gemm128(
    const bf16_t* __restrict__ A, const bf16_t* __restrict__ B,
    CT* __restrict__ C, bf16_t* __restrict__ CkP, bf16_t* __restrict__ CvtP,
    int N, int K)
{
    __shared__ __align__(16) bf16_t sA[128 * 64];
    __shared__ __align__(16) bf16_t sB[128 * 64];

    const int tid = threadIdx.x, lane = tid & 63, wave = tid >> 6;
    const int l16 = lane & 15, quad = lane >> 4;
    const int m0 = blockIdx.y * 128, n0 = blockIdx.x * 128;
    const int wm = (wave >> 1) * 64, wn = (wave & 1) * 64;

    const bf16_t* gA[4]; const bf16_t* gB[4];
    bf16_t* lA[4]; bf16_t* lB[4];
#pragma unroll
    for (int t = 0; t < 4; t++) {
        int p = (wave * 4 + t) * 64 + lane;
        int row = p >> 3;
        int lc = (p & 7) ^ (row & 7);
        gA[t] = A + (size_t)(m0 + row) * K + lc * 8;
        gB[t] = B + (size_t)(n0 + row) * K + lc * 8;
        lA[t] = &sA[(wave * 4 + t) * 512];
        lB[t] = &sB[(wave * 4 + t) * 512];
    }

    int offA[2][4], offB[2][4];
#pragma unroll
    for (int kc = 0; kc < 2; kc++)
#pragma unroll
        for (int i = 0; i < 4; i++) {
            int rm = wm + i * 16 + l16;
            offA[kc][i] = rm * 64 + (((kc * 4 + quad) ^ (rm & 7)) * 8);
            int rn = wn + i * 16 + l16;
            offB[kc][i] = rn * 64 + (((kc * 4 + quad) ^ (rn & 7)) * 8);
        }

    f32x4 acc[4][4] = {};

    for (int k0 = 0; k0 < K; k0 += 64) {
        __syncthreads();
#pragma unroll
        for (int t = 0; t < 4; t++) {
            gll16(gA[t], lA[t]);
            gll16(gB[t], lB[t]);
            gA[t] += 64; gB[t] += 64;
        }
        __syncthreads();

#pragma unroll
        for (int kc = 0; kc < 2; kc++) {
            bf16x8 af[4], bfv[4];
#pragma unroll
            for (int i = 0; i < 4; i++) af[i] = *(bf16x8*)&sA[offA[kc][i]];
#pragma unroll
            for (int j = 0; j < 4; j++) bfv[j] = *(bf16x8*)&sB[offB[kc][j]];
#pragma unroll
            for (int i = 0; i < 4; i++)
#pragma unroll
                for (int j = 0; j < 4; j++)
                    acc[i][j] = __builtin_amdgcn_mfma_f32_16x16x32_bf16(af[i], bfv[j], acc[i][j], 0, 0, 0);
        }
    }

#pragma unroll
    for (int i = 0; i < 4; i++) {
        int rowb = m0 + wm + i * 16 + quad * 4;
#pragma unroll
        for (int j = 0; j < 4; j++) {
            int col = n0 + wn + j * 16 + l16;
#pragma unroll
            for (int r = 0; r < 4; r++) {
                float v = acc[i][j][r];
                int row = rowb + r;
                if (MODE == 0) {
                    C[(size_t)row * N + col] = (CT)v;
                } else {
                    if (col < 2048)      C[(size_t)row * 2048 + col] = (CT)v;
                    else if (col < 2560) CkP[(size_t)row * 512 + (col - 2048)] = (bf16_t)v;
                    else                 CvtP[(size_t)(col - 2560) * S_LEN + row] = (bf16_t)v;
                }
            }
        }
    }
}

// ---------------------------------------------------------------------------
// Fused RoPE over q (16 heads) and k (4 heads): grid (S, 5), block 128.
// ---------------------------------------------------------------------------
__global__ void rope_all(bf16_t* __restrict__ Qh, bf16_t* __restrict__ Kh,
                         const float* __restrict__ cosb, const float* __restrict__ sinb)
{
    int s = blockIdx.x;
    int grp = blockIdx.y;
    int sub = threadIdx.x >> 5;
    int i = threadIdx.x & 31;
    bf16_t* row = (grp < 4) ? (Qh + ((size_t)s * NH + grp * 4 + sub) * HD)
                            : (Kh + ((size_t)s * NKV + sub) * HD);
    float x0 = (float)row[2 * i];
    float x1 = (float)row[2 * i + 1];
    float p0 = (float)row[64 + 2 * i];
    float p1 = (float)row[64 + 2 * i + 1];
    float c0 = cosb[s * HD + 2 * i];
    float c1 = cosb[s * HD + 2 * i + 1];
    float n0 = sinb[s * HD + 2 * i];
    float n1 = sinb[s * HD + 2 * i + 1];
    float r0 = -x1, r1 = x0;
    row[2 * i]          = (bf16_t)(r0 * c0 + p0 * n0);
    row[2 * i + 1]      = (bf16_t)(r1 * c1 + p1 * n1);
    row[64 + 2 * i]     = (bf16_t)(-r0 * n0 + p0 * c0);
    row[64 + 2 * i + 1] = (bf16_t)(-r1 * n1 + p1 * c1);
}

// ---------------------------------------------------------------------------
// Flash attention v6: VARIABLE causal key-split for load balance.
//   qt < 16 : split-2 (critical path <= 8 iters), partials z=0,1
//   qt >= 16: split-4 (critical path <= 8 iters), partials z=0..3
// Grid (96, NKV) = 384 blocks -> 2 co-resident blocks on half the CUs
// (independent barriers overlap stalls). Dataflow identical to R9's flash5:
// wave = 16 q-rows x 4 heads, hoisted kf/vf reads, swapped-operand QK,
// packed b64 P writes, unnormalized partials + deferred combine.
// Partial storage: z=0,1 full-size (OpLo, d_out); z=2,3 rows>=1024 only
// (OpHi, wb region — dead between gemm_qkv and wo-cvt).
// ---------------------------------------------------------------------------
__global__ __launch_bounds__(256, 1) void flash_attn6(
    const bf16_t* __restrict__ Q,   // S x (NH*HD)
    const bf16_t* __restrict__ Kb,  // S x (NKV*HD)
    const bf16_t* __restrict__ VT,  // (NKV*HD) x S
    bf16_t* __restrict__ OpLo,      // 2 x S x HID (z=0,1)
    bf16_t* __restrict__ OpHi,      // 2 x 1024 x HID (z=2,3; rows 1024..2047)
    float* __restrict__ lpart,      // 4 x S x NH
    int S)
{
    __shared__ __align__(16) bf16_t sK[64 * 136];
    __shared__ __align__(16) bf16_t sVT[128 * 72];
    __shared__ __align__(16) bf16_t sP[4][16 * 72];  // per-wave scratch

    // block -> (qt, z, nsplit)
    const int bx = blockIdx.x;
    int qt, z, nsplit;
    if (bx < 32) { qt = bx >> 1;        z = bx & 1; nsplit = 2; }
    else         { qt = 16 + ((bx - 32) >> 2); z = (bx - 32) & 3; nsplit = 4; }

    const int kvh = blockIdx.y;
    const int h0  = kvh * 4;
    const int q0  = qt * 64;
    const int tid = threadIdx.x, lane = tid & 63, wave = tid >> 6;
    const int l16 = lane & 15, quad = lane >> 4;
    const float scale = 0.08838834764831845f;  // 1/sqrt(128)

    const int nkt = qt + 1;
    const int tb  = (z * nkt) / nsplit;
    const int te  = ((z + 1) * nkt) / nsplit;

    const int qrow = q0 + wave * 16 + l16;

    // Q fragments: 4 heads (B-operand of swapped QK)
    bf16x8 qf[4][4];
#pragma unroll
    for (int h = 0; h < 4; h++)
#pragma unroll
        for (int c = 0; c < 4; c++)
            qf[h][c] = *(const bf16x8*)&Q[(size_t)qrow * HID + (h0 + h) * HD + c * 32 + quad * 8];

    f32x4 oacc[4][8] = {};
    float lsum[4] = {0.f, 0.f, 0.f, 0.f};

    int krow[4], kcol[4], vrow[4], vcol[4];
#pragma unroll
    for (int it = 0; it < 4; it++) {
        int c = tid + 256 * it;
        krow[it] = c >> 4; kcol[it] = (c & 15) * 8;
        vrow[it] = c >> 3; vcol[it] = (c & 7) * 8;
    }

    // prefetch first tile of this block's range (valid memory even if empty)
    bf16x8 kpre[4], vpre[4];
#pragma unroll
    for (int it = 0; it < 4; it++) {
        kpre[it] = *(const bf16x8*)&Kb[(size_t)(tb * 64 + krow[it]) * (NKV * HD) + kvh * HD + kcol[it]];
        vpre[it] = *(const bf16x8*)&VT[((size_t)kvh * HD + vrow[it]) * S + tb * 64 + vcol[it]];
    }

    for (int kt = tb; kt < te; kt++) {
        const int t0 = kt * 64;
        __syncthreads();
#pragma unroll
        for (int it = 0; it < 4; it++) {
            *(bf16x8*)&sK[krow[it] * 136 + kcol[it]] = kpre[it];
            *(bf16x8*)&sVT[vrow[it] * 72 + vcol[it]] = vpre[it];
        }
        __syncthreads();

        if (kt + 1 < te) {
            const int t1 = t0 + 64;
#pragma unroll
            for (int it = 0; it < 4; it++) {
                kpre[it] = *(const bf16x8*)&Kb[(size_t)(t1 + krow[it]) * (NKV * HD) + kvh * HD + kcol[it]];
                vpre[it] = *(const bf16x8*)&VT[((size_t)kvh * HD + vrow[it]) * S + t1 + vcol[it]];
            }
        }

        // ---- QK^T (swapped): nt outer, kf read ONCE, 4 heads share it ----
        f32x4 sc[4][4];   // [h][nt]
#pragma unroll
        for (int nt = 0; nt < 4; nt++) {
            bf16x8 kf[4];
#pragma unroll
            for (int c = 0; c < 4; c++)
                kf[c] = *(bf16x8*)&sK[(nt * 16 + l16) * 136 + c * 32 + quad * 8];
#pragma unroll
            for (int h = 0; h < 4; h++) {
                f32x4 d = {};
#pragma unroll
                for (int c = 0; c < 4; c++)
                    d = __builtin_amdgcn_mfma_f32_16x16x32_bf16(kf[c], qf[h][c], d, 0, 0, 0);
                sc[h][nt] = d;
            }
        }

        // ---- exp + packed P write + A-frag read, per head (wave-private) ----
        bf16x8 pa[4][2];
#pragma unroll
        for (int h = 0; h < 4; h++) {
#pragma unroll
            for (int nt = 0; nt < 4; nt++) {
                const int tbk = t0 + nt * 16 + quad * 4;
                bf16x4 pk;
#pragma unroll
                for (int r = 0; r < 4; r++) {
                    float p = (tbk + r <= qrow) ? __expf(sc[h][nt][r] * scale) : 0.0f;
                    lsum[h] += p;
                    pk[r] = (bf16_t)p;
                }
                *(bf16x4*)&sP[wave][l16 * 72 + nt * 16 + quad * 4] = pk;
            }
#pragma unroll
            for (int kc = 0; kc < 2; kc++)
                pa[h][kc] = *(bf16x8*)&sP[wave][l16 * 72 + kc * 32 + quad * 8];
        }

        // ---- PV: dt outer, vf read ONCE, 4 heads share it ----
#pragma unroll
        for (int dt = 0; dt < 8; dt++)
#pragma unroll
            for (int kc = 0; kc < 2; kc++) {
                bf16x8 vf = *(bf16x8*)&sVT[(dt * 16 + l16) * 72 + kc * 32 + quad * 8];
#pragma unroll
                for (int h = 0; h < 4; h++)
                    oacc[h][dt] = __builtin_amdgcn_mfma_f32_16x16x32_bf16(pa[h][kc], vf, oacc[h][dt], 0, 0, 0);
            }
    }

    // epilogue: store UNNORMALIZED partial O + partial l
    bf16_t* Op;
    int rbase;   // row index offset within the partial buffer
    if (z < 2) { Op = OpLo + (size_t)z * S * HID;            rbase = q0; }
    else       { Op = OpHi + (size_t)(z - 2) * 1024 * HID;   rbase = q0 - 1024; }

#pragma unroll
    for (int h = 0; h < 4; h++) {
        float lr = lsum[h];
        lr += __shfl_xor(lr, 16, 64);
        lr += __shfl_xor(lr, 32, 64);   // lane L: l for row offset L&15
        if (quad == 0)
            lpart[((size_t)z * S + q0 + wave * 16 + l16) * NH + (h0 + h)] = lr;
#pragma unroll
        for (int r = 0; r < 4; r++) {
            int prow = rbase + wave * 16 + quad * 4 + r;
#pragma unroll
            for (int dt = 0; dt < 8; dt++)
                Op[(size_t)prow * HID + (h0 + h) * HD + dt * 16 + l16] =
                    (bf16_t)(oacc[h][dt][r]);
        }
    }
}

// ---------------------------------------------------------------------------
// Combine: oh = sum(Opart_z) / sum(l_z).  2 partials for s<1024, 4 otherwise.
// ---------------------------------------------------------------------------
__global__ __launch_bounds__(256) void flash_combine(
    const bf16_t* __restrict__ OpLo, const bf16_t* __restrict__ OpHi,
    const float* __restrict__ lpart, bf16_t* __restrict__ oh)
{
    int i = (blockIdx.x * 256 + threadIdx.x) * 8;
    int s = i >> 11;            // row (2048 cols)
    int h = (i >> 7) & 15;      // head
    float l = lpart[(size_t)s * NH + h] + lpart[((size_t)S_LEN + s) * NH + h];
    bf16x8 a = *(const bf16x8*)&OpLo[i];
    bf16x8 b = *(const bf16x8*)&OpLo[(size_t)S_LEN * HID + i];
    float v[8];
#pragma unroll
    for (int j = 0; j < 8; j++) v[j] = (float)a[j] + (float)b[j];
    if (s >= 1024) {
        l += lpart[((size_t)2 * S_LEN + s) * NH + h] + lpart[((size_t)3 * S_LEN + s) * NH + h];
        size_t ih = (size_t)i - (size_t)1024 * HID;
        bf16x8 c = *(const bf16x8*)&OpHi[ih];
        bf16x8 d = *(const bf16x8*)&OpHi[(size_t)1024 * HID + ih];
#pragma unroll
        for (int j = 0; j < 8; j++) v[j] += (float)c[j] + (float)d[j];
    }
    float inv = 1.0f / l;
    bf16x8 o;
#pragma unroll
    for (int j = 0; j < 8; j++) o[j] = (bf16_t)(v[j] * inv);
    *(bf16x8*)&oh[i] = o;
}

// ---------------------------------------------------------------------------
extern "C" void kernel_launch(void* const* d_in, const int* in_sizes, int n_in,
                              void* d_out, int out_size, void* d_ws, size_t ws_size,
                              hipStream_t stream)
{
    const float* x    = (const float*)d_in[0];
    const float* cosb = (const float*)d_in[1];
    const float* sinb = (const float*)d_in[2];
    const float* wq   = (const float*)d_in[3];
    const float* wk   = (const float*)d_in[4];
    const float* wv   = (const float*)d_in[5];
    const float* wo   = (const float*)d_in[6];
    float* out = (float*)d_out;

    // Workspace (24.5 MB peak; 28 MB proven available in R3):
    char* ws = (char*)d_ws;
    bf16_t* wb = (bf16_t*)(ws);                              // 0..12 MB: [wq;wk;wv] bf16; flash partials z=2,3; then wo bf16
    bf16_t* qh = (bf16_t*)(ws + (size_t)12 * 1024 * 1024);   // 12..20 MB: q / attn-out
    bf16_t* kh = (bf16_t*)(ws + (size_t)20 * 1024 * 1024);   // 20..22 MB: k
    bf16_t* vT = (bf16_t*)(ws + (size_t)22 * 1024 * 1024);   // 22..24 MB: v^T
    float*  lp = (float*) (ws + (size_t)24 * 1024 * 1024);   // 24..24.5 MB: partial l (4 slices)
    // d_out (16 MB) doubles as scratch: x bf16 (steps 1-3), then O partials z=0,1.
    bf16_t* xb   = (bf16_t*)d_out;
    bf16_t* opLo = (bf16_t*)d_out;           // 2 x 8 MB
    bf16_t* opHi = wb;                       // 2 x 4 MB (rows 1024..2047), wb dead here

    const int NX = S_LEN * HID;   // 4 Mi

    // 1) x -> bf16 (into d_out scratch)
    cvt_f32_bf16<<<NX / (256 * 8), 256, 0, stream>>>(x, xb, NX);

    // 2) weights -> bf16
    cvt_w3<<<6 * 1024 * 1024 / (256 * 8), 256, 0, stream>>>(wq, wk, wv, wb);

    // 3) fused QKV GEMM (all-bf16, m97 recipe), routed outputs. grid 24x16.
    gemm128<1, bf16_t><<<dim3(24, 16), 256, 0, stream>>>(xb, wb, qh, kh, vT, 3072, HID);

    // 4) RoPE on q + k
    rope_all<<<dim3(S_LEN, 5), 128, 0, stream>>>(qh, kh, cosb, sinb);

    // 5) flash attention v6, variable key-split -> partials (xb, wb now dead)
    flash_attn6<<<dim3(96, NKV), 256, 0, stream>>>(qh, kh, vT, opLo, opHi, lp, S_LEN);

    // 6) combine partials -> qh (attn output, normalized bf16)
    flash_combine<<<NX / (256 * 8), 256, 0, stream>>>(opLo, opHi, lp, qh);

    // 7) wo -> bf16 (reuses wb; partials z=2,3 consumed by combine)
    cvt_f32_bf16<<<NX / (256 * 8), 256, 0, stream>>>(wo, wb, NX);

    // 8) out = attn_out @ wo^T -> fp32 d_out (overwrites partials). grid 16x16.
    gemm128<0, float><<<dim3(16, 16), 256, 0, stream>>>(qh, wb, out, nullptr, nullptr, HID, HID);
}

// Round 11
// 248.859 us; speedup vs baseline: 1.0180x; 1.0180x over previous
//
#include <hip/hip_runtime.h>
#include <hip/hip_bf16.h>

// Shapes (fixed): B=1, S=2048, HID=2048, NH=16, NKV=4, HD=128
// Inputs: fp32. Output: fp32. Internal compute: bf16 MFMA, fp32 accumulate.
typedef __bf16 bf16_t;
typedef __attribute__((ext_vector_type(8))) __bf16 bf16x8;
typedef __attribute__((ext_vector_type(4))) __bf16 bf16x4;
typedef __attribute__((ext_vector_type(4))) float f32x4;

#define S_LEN 2048
#define HID 2048
#define NH 16
#define NKV 4
#define HD 128

__device__ __forceinline__ void gll16(const bf16_t* g, bf16_t* l) {
    __builtin_amdgcn_global_load_lds(
        (const __attribute__((address_space(1))) unsigned int*)g,
        (__attribute__((address_space(3))) unsigned int*)l, 16, 0, 0);
}

__device__ __forceinline__ bf16x8 cvt2x4(float4 a, float4 b) {
    bf16x8 o;
    o[0]=(bf16_t)a.x; o[1]=(bf16_t)a.y; o[2]=(bf16_t)a.z; o[3]=(bf16_t)a.w;
    o[4]=(bf16_t)b.x; o[5]=(bf16_t)b.y; o[6]=(bf16_t)b.z; o[7]=(bf16_t)b.w;
    return o;
}

// ---------------------------------------------------------------------------
__global__ __launch_bounds__(256) void cvt_f32_bf16(const float* __restrict__ in,
                                                    bf16_t* __restrict__ out, int n)
{
    int i = (blockIdx.x * 256 + threadIdx.x) * 8;
    if (i >= n) return;
    float4 a = *(const float4*)&in[i];
    float4 b = *(const float4*)&in[i + 4];
    *(bf16x8*)&out[i] = cvt2x4(a, b);
}

// Fused weight conversion: [wq | wk | wv] fp32 -> contiguous bf16 (3072 x 2048)
__global__ __launch_bounds__(256) void cvt_w3(const float* __restrict__ wq,
                                              const float* __restrict__ wk,
                                              const float* __restrict__ wv,
                                              bf16_t* __restrict__ out)
{
    int i = (blockIdx.x * 256 + threadIdx.x) * 8;
    const float* src; int off;
    if (i < 4 * 1024 * 1024)      { src = wq; off = i; }
    else if (i < 5 * 1024 * 1024) { src = wk; off = i - 4 * 1024 * 1024; }
    else                          { src = wv; off = i - 5 * 1024 * 1024; }
    float4 a = *(const float4*)&src[off];
    float4 b = *(const float4*)&src[off + 4];
    *(bf16x8*)&out[i] = cvt2x4(a, b);
}

// ---------------------------------------------------------------------------
// m97-recipe NT GEMM (unchanged): 128x128 tile, BK=64, 32 MFMA/iter,
// gll width-16 staging, XOR-swizzled unpadded LDS.
// MODE 0: C fp32 row-major. MODE 1: qkv routing (C=q bf16 / Ck / Cvt^T).
// ---------------------------------------------------------------------------
template<int MODE, typename CT>
__global__ __launch_bounds__(256, 2) void gemm128(
    const bf16_t* __restrict__ A, const bf16_t* __restrict__ B,
    CT* __restrict__ C, bf16_t* __restrict__ CkP, bf16_t* __restrict__ CvtP,
    int N, int K)
{
    __shared__ __align__(16) bf16_t sA[128 * 64];
    __shared__ __align__(16) bf16_t sB[128 * 64];

    const int tid = threadIdx.x, lane = tid & 63, wave = tid >> 6;
    const int l16 = lane & 15, quad = lane >> 4;
    const int m0 = blockIdx.y * 128, n0 = blockIdx.x * 128;
    const int wm = (wave >> 1) * 64, wn = (wave & 1) * 64;

    const bf16_t* gA[4]; const bf16_t* gB[4];
    bf16_t* lA[4]; bf16_t* lB[4];
#pragma unroll
    for (int t = 0; t < 4; t++) {
        int p = (wave * 4 + t) * 64 + lane;
        int row = p >> 3;
        int lc = (p & 7) ^ (row & 7);
        gA[t] = A + (size_t)(m0 + row) * K + lc * 8;
        gB[t] = B + (size_t)(n0 + row) * K + lc * 8;
        lA[t] = &sA[(wave * 4 + t) * 512];
        lB[t] = &sB[(wave * 4 + t) * 512];
    }

    int offA[2][4], offB[2][4];
#pragma unroll
    for (int kc = 0; kc < 2; kc++)
#pragma unroll
        for (int i = 0; i < 4; i++) {
            int rm = wm + i * 16 + l16;
            offA[kc][i] = rm * 64 + (((kc * 4 + quad) ^ (rm & 7)) * 8);
            int rn = wn + i * 16 + l16;
            offB[kc][i] = rn * 64 + (((kc * 4 + quad) ^ (rn & 7)) * 8);
        }

    f32x4 acc[4][4] = {};

    for (int k0 = 0; k0 < K; k0 += 64) {
        __syncthreads();
#pragma unroll
        for (int t = 0; t < 4; t++) {
            gll16(gA[t], lA[t]);
            gll16(gB[t], lB[t]);
            gA[t] += 64; gB[t] += 64;
        }
        __syncthreads();

#pragma unroll
        for (int kc = 0; kc < 2; kc++) {
            bf16x8 af[4], bfv[4];
#pragma unroll
            for (int i = 0; i < 4; i++) af[i] = *(bf16x8*)&sA[offA[kc][i]];
#pragma unroll
            for (int j = 0; j < 4; j++) bfv[j] = *(bf16x8*)&sB[offB[kc][j]];
#pragma unroll
            for (int i = 0; i < 4; i++)
#pragma unroll
                for (int j = 0; j < 4; j++)
                    acc[i][j] = __builtin_amdgcn_mfma_f32_16x16x32_bf16(af[i], bfv[j], acc[i][j], 0, 0, 0);
        }
    }

#pragma unroll
    for (int i = 0; i < 4; i++) {
        int rowb = m0 + wm + i * 16 + quad * 4;
#pragma unroll
        for (int j = 0; j < 4; j++) {
            int col = n0 + wn + j * 16 + l16;
#pragma unroll
            for (int r = 0; r < 4; r++) {
                float v = acc[i][j][r];
                int row = rowb + r;
                if (MODE == 0) {
                    C[(size_t)row * N + col] = (CT)v;
                } else {
                    if (col < 2048)      C[(size_t)row * 2048 + col] = (CT)v;
                    else if (col < 2560) CkP[(size_t)row * 512 + (col - 2048)] = (bf16_t)v;
                    else                 CvtP[(size_t)(col - 2560) * S_LEN + row] = (bf16_t)v;
                }
            }
        }
    }
}

// ---------------------------------------------------------------------------
// Fused RoPE over q (16 heads) and k (4 heads): grid (S, 5), block 128.
// ---------------------------------------------------------------------------
__global__ void rope_all(bf16_t* __restrict__ Qh, bf16_t* __restrict__ Kh,
                         const float* __restrict__ cosb, const float* __restrict__ sinb)
{
    int s = blockIdx.x;
    int grp = blockIdx.y;
    int sub = threadIdx.x >> 5;
    int i = threadIdx.x & 31;
    bf16_t* row = (grp < 4) ? (Qh + ((size_t)s * NH + grp * 4 + sub) * HD)
                            : (Kh + ((size_t)s * NKV + sub) * HD);
    float x0 = (float)row[2 * i];
    float x1 = (float)row[2 * i + 1];
    float p0 = (float)row[64 + 2 * i];
    float p1 = (float)row[64 + 2 * i + 1];
    float c0 = cosb[s * HD + 2 * i];
    float c1 = cosb[s * HD + 2 * i + 1];
    float n0 = sinb[s * HD + 2 * i];
    float n1 = sinb[s * HD + 2 * i + 1];
    float r0 = -x1, r1 = x0;
    row[2 * i]          = (bf16_t)(r0 * c0 + p0 * n0);
    row[2 * i + 1]      = (bf16_t)(r1 * c1 + p1 * n1);
    row[64 + 2 * i]     = (bf16_t)(-r0 * n0 + p0 * c0);
    row[64 + 2 * i + 1] = (bf16_t)(-r1 * n1 + p1 * c1);
}

// ---------------------------------------------------------------------------
// Flash attention v7: R9's split-2 shape (grid (32, NKV, 2) = 256 blocks,
// 1 block/CU) + LDS DOUBLE-BUFFERED K/V tiles: tile k+1 is written to
// buf[sel^1] DURING compute of buf[sel] -> ONE barrier per iter (was 2),
// staging writes overlap MFMA/VALU. Alternation pushes the write-read hazard
// two iters back (prev reads of buf[sel^1] fenced by the prior barrier).
// Interior tiles (kt < qt) skip the causal compare (always unmasked);
// only the diagonal tile (kt == qt, in z=1) pays the mask.
// Dataflow otherwise identical to R9 flash5 (verified): wave = 16 q-rows x
// 4 heads, hoisted kf/vf reads, swapped-operand QK, packed b64 P writes,
// unnormalized partials + deferred combine. No max-tracking.
// ---------------------------------------------------------------------------
__global__ __launch_bounds__(256, 1) void flash_attn7(
    const bf16_t* __restrict__ Q,   // S x (NH*HD)
    const bf16_t* __restrict__ Kb,  // S x (NKV*HD)
    const bf16_t* __restrict__ VT,  // (NKV*HD) x S
    bf16_t* __restrict__ Opart,     // 2 x S x (NH*HD), unnormalized
    float* __restrict__ lpart,      // 2 x S x NH
    int S)
{
    __shared__ __align__(16) bf16_t sK[2][64 * 136];   // 2 x 17 KB
    __shared__ __align__(16) bf16_t sVT[2][128 * 72];  // 2 x 18 KB
    __shared__ __align__(16) bf16_t sP[4][16 * 72];    // 9 KB, wave-private

    const int qt  = blockIdx.x;
    const int kvh = blockIdx.y;
    const int z   = blockIdx.z;
    const int h0  = kvh * 4;
    const int q0  = qt * 64;
    const int tid = threadIdx.x, lane = tid & 63, wave = tid >> 6;
    const int l16 = lane & 15, quad = lane >> 4;
    const float scale = 0.08838834764831845f;  // 1/sqrt(128)

    const int nkt = qt + 1;
    const int hc  = nkt >> 1;
    const int tb  = z ? hc : 0;
    const int te  = z ? nkt : hc;

    const int qrow = q0 + wave * 16 + l16;

    // Q fragments: 4 heads (B-operand of swapped QK)
    bf16x8 qf[4][4];
#pragma unroll
    for (int h = 0; h < 4; h++)
#pragma unroll
        for (int c = 0; c < 4; c++)
            qf[h][c] = *(const bf16x8*)&Q[(size_t)qrow * HID + (h0 + h) * HD + c * 32 + quad * 8];

    f32x4 oacc[4][8] = {};
    float lsum[4] = {0.f, 0.f, 0.f, 0.f};

    int krow[4], kcol[4], vrow[4], vcol[4];
#pragma unroll
    for (int it = 0; it < 4; it++) {
        int c = tid + 256 * it;
        krow[it] = c >> 4; kcol[it] = (c & 15) * 8;
        vrow[it] = c >> 3; vcol[it] = (c & 7) * 8;
    }

    // prologue: tile tb -> regs -> buf0; prefetch tb+1 into regs
    bf16x8 kpre[4], vpre[4];
#pragma unroll
    for (int it = 0; it < 4; it++) {
        kpre[it] = *(const bf16x8*)&Kb[(size_t)(tb * 64 + krow[it]) * (NKV * HD) + kvh * HD + kcol[it]];
        vpre[it] = *(const bf16x8*)&VT[((size_t)kvh * HD + vrow[it]) * S + tb * 64 + vcol[it]];
    }
#pragma unroll
    for (int it = 0; it < 4; it++) {
        *(bf16x8*)&sK[0][krow[it] * 136 + kcol[it]] = kpre[it];
        *(bf16x8*)&sVT[0][vrow[it] * 72 + vcol[it]] = vpre[it];
    }
    if (tb + 1 < te) {
        const int t1 = (tb + 1) * 64;
#pragma unroll
        for (int it = 0; it < 4; it++) {
            kpre[it] = *(const bf16x8*)&Kb[(size_t)(t1 + krow[it]) * (NKV * HD) + kvh * HD + kcol[it]];
            vpre[it] = *(const bf16x8*)&VT[((size_t)kvh * HD + vrow[it]) * S + t1 + vcol[it]];
        }
    }
    __syncthreads();

    int sel = 0;
    for (int kt = tb; kt < te; kt++) {
        const int t0 = kt * 64;
        const int ns = sel ^ 1;

        // stage tile kt+1 into the OTHER buffer (overlaps this iter's compute;
        // prior reads of buf[ns] were fenced by the previous barrier)
        if (kt + 1 < te) {
#pragma unroll
            for (int it = 0; it < 4; it++) {
                *(bf16x8*)&sK[ns][krow[it] * 136 + kcol[it]] = kpre[it];
                *(bf16x8*)&sVT[ns][vrow[it] * 72 + vcol[it]] = vpre[it];
            }
            if (kt + 2 < te) {
                const int t2 = t0 + 128;
#pragma unroll
                for (int it = 0; it < 4; it++) {
                    kpre[it] = *(const bf16x8*)&Kb[(size_t)(t2 + krow[it]) * (NKV * HD) + kvh * HD + kcol[it]];
                    vpre[it] = *(const bf16x8*)&VT[((size_t)kvh * HD + vrow[it]) * S + t2 + vcol[it]];
                }
            }
        }

        // ---- QK^T (swapped): nt outer, kf read ONCE, 4 heads share it ----
        f32x4 sc[4][4];   // [h][nt]
#pragma unroll
        for (int nt = 0; nt < 4; nt++) {
            bf16x8 kf[4];
#pragma unroll
            for (int c = 0; c < 4; c++)
                kf[c] = *(bf16x8*)&sK[sel][(nt * 16 + l16) * 136 + c * 32 + quad * 8];
#pragma unroll
            for (int h = 0; h < 4; h++) {
                f32x4 d = {};
#pragma unroll
                for (int c = 0; c < 4; c++)
                    d = __builtin_amdgcn_mfma_f32_16x16x32_bf16(kf[c], qf[h][c], d, 0, 0, 0);
                sc[h][nt] = d;
            }
        }

        // ---- exp + packed P write + A-frag read (wave-private sP) ----
        bf16x8 pa[4][2];
        if (kt == qt) {
            // diagonal tile: causal mask needed
#pragma unroll
            for (int h = 0; h < 4; h++) {
#pragma unroll
                for (int nt = 0; nt < 4; nt++) {
                    const int tbk = t0 + nt * 16 + quad * 4;
                    bf16x4 pk;
#pragma unroll
                    for (int r = 0; r < 4; r++) {
                        float p = (tbk + r <= qrow) ? __expf(sc[h][nt][r] * scale) : 0.0f;
                        lsum[h] += p;
                        pk[r] = (bf16_t)p;
                    }
                    *(bf16x4*)&sP[wave][l16 * 72 + nt * 16 + quad * 4] = pk;
                }
#pragma unroll
                for (int kc = 0; kc < 2; kc++)
                    pa[h][kc] = *(bf16x8*)&sP[wave][l16 * 72 + kc * 32 + quad * 8];
            }
        } else {
            // interior tile: all keys <= all q-rows, no compare
#pragma unroll
            for (int h = 0; h < 4; h++) {
#pragma unroll
                for (int nt = 0; nt < 4; nt++) {
                    bf16x4 pk;
#pragma unroll
                    for (int r = 0; r < 4; r++) {
                        float p = __expf(sc[h][nt][r] * scale);
                        lsum[h] += p;
                        pk[r] = (bf16_t)p;
                    }
                    *(bf16x4*)&sP[wave][l16 * 72 + nt * 16 + quad * 4] = pk;
                }
#pragma unroll
                for (int kc = 0; kc < 2; kc++)
                    pa[h][kc] = *(bf16x8*)&sP[wave][l16 * 72 + kc * 32 + quad * 8];
            }
        }

        // ---- PV: dt outer, vf read ONCE, 4 heads share it ----
#pragma unroll
        for (int dt = 0; dt < 8; dt++)
#pragma unroll
            for (int kc = 0; kc < 2; kc++) {
                bf16x8 vf = *(bf16x8*)&sVT[sel][(dt * 16 + l16) * 72 + kc * 32 + quad * 8];
#pragma unroll
                for (int h = 0; h < 4; h++)
                    oacc[h][dt] = __builtin_amdgcn_mfma_f32_16x16x32_bf16(pa[h][kc], vf, oacc[h][dt], 0, 0, 0);
            }

        __syncthreads();   // buf[ns] writes visible; buf[sel] reads done
        sel = ns;
    }

    // epilogue: store UNNORMALIZED partial O + partial l
    bf16_t* Op = Opart + (size_t)z * S * HID;
#pragma unroll
    for (int h = 0; h < 4; h++) {
        float lr = lsum[h];
        lr += __shfl_xor(lr, 16, 64);
        lr += __shfl_xor(lr, 32, 64);   // lane L: l for row offset L&15
        if (quad == 0)
            lpart[((size_t)z * S + q0 + wave * 16 + l16) * NH + (h0 + h)] = lr;
#pragma unroll
        for (int r = 0; r < 4; r++) {
            int srow = q0 + wave * 16 + quad * 4 + r;
#pragma unroll
            for (int dt = 0; dt < 8; dt++)
                Op[(size_t)srow * HID + (h0 + h) * HD + dt * 16 + l16] =
                    (bf16_t)(oacc[h][dt][r]);
        }
    }
}

// ---------------------------------------------------------------------------
// Combine: oh = (O0 + O1) / (l0 + l1). 8 elems/thread (within one head).
// ---------------------------------------------------------------------------
__global__ __launch_bounds__(256) void flash_combine(
    const bf16_t* __restrict__ Opart, const float* __restrict__ lpart,
    bf16_t* __restrict__ oh)
{
    int i = (blockIdx.x * 256 + threadIdx.x) * 8;
    int s = i >> 11;            // row (2048 cols)
    int h = (i >> 7) & 15;      // head
    float l = lpart[(size_t)s * NH + h] + lpart[((size_t)S_LEN + s) * NH + h];
    float inv = 1.0f / l;
    bf16x8 a = *(const bf16x8*)&Opart[i];
    bf16x8 b = *(const bf16x8*)&Opart[(size_t)S_LEN * HID + i];
    bf16x8 o;
#pragma unroll
    for (int j = 0; j < 8; j++)
        o[j] = (bf16_t)(((float)a[j] + (float)b[j]) * inv);
    *(bf16x8*)&oh[i] = o;
}

// ---------------------------------------------------------------------------
extern "C" void kernel_launch(void* const* d_in, const int* in_sizes, int n_in,
                              void* d_out, int out_size, void* d_ws, size_t ws_size,
                              hipStream_t stream)
{
    const float* x    = (const float*)d_in[0];
    const float* cosb = (const float*)d_in[1];
    const float* sinb = (const float*)d_in[2];
    const float* wq   = (const float*)d_in[3];
    const float* wk   = (const float*)d_in[4];
    const float* wv   = (const float*)d_in[5];
    const float* wo   = (const float*)d_in[6];
    float* out = (float*)d_out;

    // Workspace (24.25 MB):
    char* ws = (char*)d_ws;
    bf16_t* wb = (bf16_t*)(ws);                              // 0..12 MB: [wq;wk;wv] bf16 (reused for wo)
    bf16_t* qh = (bf16_t*)(ws + (size_t)12 * 1024 * 1024);   // 12..20 MB: q / attn-out
    bf16_t* kh = (bf16_t*)(ws + (size_t)20 * 1024 * 1024);   // 20..22 MB: k
    bf16_t* vT = (bf16_t*)(ws + (size_t)22 * 1024 * 1024);   // 22..24 MB: v^T
    float*  lp = (float*) (ws + (size_t)24 * 1024 * 1024);   // 24..24.25 MB: partial l
    // d_out (16 MB) doubles as scratch: x bf16 (steps 1-3), then O partials.
    bf16_t* xb = (bf16_t*)d_out;
    bf16_t* op = (bf16_t*)d_out;   // 2 x 8 MB bf16 partial O

    const int NX = S_LEN * HID;   // 4 Mi

    // 1) x -> bf16 (into d_out scratch)
    cvt_f32_bf16<<<NX / (256 * 8), 256, 0, stream>>>(x, xb, NX);

    // 2) weights -> bf16
    cvt_w3<<<6 * 1024 * 1024 / (256 * 8), 256, 0, stream>>>(wq, wk, wv, wb);

    // 3) fused QKV GEMM (all-bf16, m97 recipe), routed outputs. grid 24x16.
    gemm128<1, bf16_t><<<dim3(24, 16), 256, 0, stream>>>(xb, wb, qh, kh, vT, 3072, HID);

    // 4) RoPE on q + k
    rope_all<<<dim3(S_LEN, 5), 128, 0, stream>>>(qh, kh, cosb, sinb);

    // 5) flash attention v7, key-split x2, dbuf LDS -> partials (xb now dead)
    flash_attn7<<<dim3(32, NKV, 2), 256, 0, stream>>>(qh, kh, vT, op, lp, S_LEN);

    // 6) combine partials -> qh (attn output, normalized bf16)
    flash_combine<<<NX / (256 * 8), 256, 0, stream>>>(op, lp, qh);

    // 7) wo -> bf16 (reuses wb)
    cvt_f32_bf16<<<NX / (256 * 8), 256, 0, stream>>>(wo, wb, NX);

    // 8) out = attn_out @ wo^T -> fp32 d_out (overwrites partials). grid 16x16.
    gemm128<0, float><<<dim3(16, 16), 256, 0, stream>>>(qh, wb, out, nullptr, nullptr, HID, HID);
}

// Round 12
// 236.621 us; speedup vs baseline: 1.0707x; 1.0517x over previous
//
#include <hip/hip_runtime.h>
#include <hip/hip_bf16.h>

// Shapes (fixed): B=1, S=2048, HID=2048, NH=16, NKV=4, HD=128
// Inputs: fp32. Output: fp32. Internal compute: bf16 MFMA, fp32 accumulate.
typedef __bf16 bf16_t;
typedef __attribute__((ext_vector_type(8))) __bf16 bf16x8;
typedef __attribute__((ext_vector_type(4))) __bf16 bf16x4;
typedef __attribute__((ext_vector_type(4))) float f32x4;

#define S_LEN 2048
#define HID 2048
#define NH 16
#define NKV 4
#define HD 128

__device__ __forceinline__ void gll16(const bf16_t* g, bf16_t* l) {
    __builtin_amdgcn_global_load_lds(
        (const __attribute__((address_space(1))) unsigned int*)g,
        (__attribute__((address_space(3))) unsigned int*)l, 16, 0, 0);
}

__device__ __forceinline__ bf16x8 cvt2x4(float4 a, float4 b) {
    bf16x8 o;
    o[0]=(bf16_t)a.x; o[1]=(bf16_t)a.y; o[2]=(bf16_t)a.z; o[3]=(bf16_t)a.w;
    o[4]=(bf16_t)b.x; o[5]=(bf16_t)b.y; o[6]=(bf16_t)b.z; o[7]=(bf16_t)b.w;
    return o;
}

// ---------------------------------------------------------------------------
__global__ __launch_bounds__(256) void cvt_f32_bf16(const float* __restrict__ in,
                                                    bf16_t* __restrict__ out, int n)
{
    int i = (blockIdx.x * 256 + threadIdx.x) * 8;
    if (i >= n) return;
    float4 a = *(const float4*)&in[i];
    float4 b = *(const float4*)&in[i + 4];
    *(bf16x8*)&out[i] = cvt2x4(a, b);
}

// Fused weight conversion: [wq | wk | wv] fp32 -> contiguous bf16 (3072 x 2048)
__global__ __launch_bounds__(256) void cvt_w3(const float* __restrict__ wq,
                                              const float* __restrict__ wk,
                                              const float* __restrict__ wv,
                                              bf16_t* __restrict__ out)
{
    int i = (blockIdx.x * 256 + threadIdx.x) * 8;
    const float* src; int off;
    if (i < 4 * 1024 * 1024)      { src = wq; off = i; }
    else if (i < 5 * 1024 * 1024) { src = wk; off = i - 4 * 1024 * 1024; }
    else                          { src = wv; off = i - 5 * 1024 * 1024; }
    float4 a = *(const float4*)&src[off];
    float4 b = *(const float4*)&src[off + 4];
    *(bf16x8*)&out[i] = cvt2x4(a, b);
}

// ---------------------------------------------------------------------------
// m97-recipe NT GEMM (unchanged): 128x128 tile, BK=64, 32 MFMA/iter,
// gll width-16 staging, XOR-swizzled unpadded LDS.
// MODE 0: C fp32 row-major. MODE 1: qkv routing (C=q bf16 / Ck / Cvt^T).
// ---------------------------------------------------------------------------
template<int MODE, typename CT>
__global__ __launch_bounds__(256, 2) void gemm128(
    const bf16_t* __restrict__ A, const bf16_t* __restrict__ B,
    CT* __restrict__ C, bf16_t* __restrict__ CkP, bf16_t* __restrict__ CvtP,
    int N, int K)
{
    __shared__ __align__(16) bf16_t sA[128 * 64];
    __shared__ __align__(16) bf16_t sB[128 * 64];

    const int tid = threadIdx.x, lane = tid & 63, wave = tid >> 6;
    const int l16 = lane & 15, quad = lane >> 4;
    const int m0 = blockIdx.y * 128, n0 = blockIdx.x * 128;
    const int wm = (wave >> 1) * 64, wn = (wave & 1) * 64;

    const bf16_t* gA[4]; const bf16_t* gB[4];
    bf16_t* lA[4]; bf16_t* lB[4];
#pragma unroll
    for (int t = 0; t < 4; t++) {
        int p = (wave * 4 + t) * 64 + lane;
        int row = p >> 3;
        int lc = (p & 7) ^ (row & 7);
        gA[t] = A + (size_t)(m0 + row) * K + lc * 8;
        gB[t] = B + (size_t)(n0 + row) * K + lc * 8;
        lA[t] = &sA[(wave * 4 + t) * 512];
        lB[t] = &sB[(wave * 4 + t) * 512];
    }

    int offA[2][4], offB[2][4];
#pragma unroll
    for (int kc = 0; kc < 2; kc++)
#pragma unroll
        for (int i = 0; i < 4; i++) {
            int rm = wm + i * 16 + l16;
            offA[kc][i] = rm * 64 + (((kc * 4 + quad) ^ (rm & 7)) * 8);
            int rn = wn + i * 16 + l16;
            offB[kc][i] = rn * 64 + (((kc * 4 + quad) ^ (rn & 7)) * 8);
        }

    f32x4 acc[4][4] = {};

    for (int k0 = 0; k0 < K; k0 += 64) {
        __syncthreads();
#pragma unroll
        for (int t = 0; t < 4; t++) {
            gll16(gA[t], lA[t]);
            gll16(gB[t], lB[t]);
            gA[t] += 64; gB[t] += 64;
        }
        __syncthreads();

#pragma unroll
        for (int kc = 0; kc < 2; kc++) {
            bf16x8 af[4], bfv[4];
#pragma unroll
            for (int i = 0; i < 4; i++) af[i] = *(bf16x8*)&sA[offA[kc][i]];
#pragma unroll
            for (int j = 0; j < 4; j++) bfv[j] = *(bf16x8*)&sB[offB[kc][j]];
#pragma unroll
            for (int i = 0; i < 4; i++)
#pragma unroll
                for (int j = 0; j < 4; j++)
                    acc[i][j] = __builtin_amdgcn_mfma_f32_16x16x32_bf16(af[i], bfv[j], acc[i][j], 0, 0, 0);
        }
    }

#pragma unroll
    for (int i = 0; i < 4; i++) {
        int rowb = m0 + wm + i * 16 + quad * 4;
#pragma unroll
        for (int j = 0; j < 4; j++) {
            int col = n0 + wn + j * 16 + l16;
#pragma unroll
            for (int r = 0; r < 4; r++) {
                float v = acc[i][j][r];
                int row = rowb + r;
                if (MODE == 0) {
                    C[(size_t)row * N + col] = (CT)v;
                } else {
                    if (col < 2048)      C[(size_t)row * 2048 + col] = (CT)v;
                    else if (col < 2560) CkP[(size_t)row * 512 + (col - 2048)] = (bf16_t)v;
                    else                 CvtP[(size_t)(col - 2560) * S_LEN + row] = (bf16_t)v;
                }
            }
        }
    }
}

// ---------------------------------------------------------------------------
// Fused RoPE over q (16 heads) and k (4 heads): grid (S, 5), block 128.
// ---------------------------------------------------------------------------
__global__ void rope_all(bf16_t* __restrict__ Qh, bf16_t* __restrict__ Kh,
                         const float* __restrict__ cosb, const float* __restrict__ sinb)
{
    int s = blockIdx.x;
    int grp = blockIdx.y;
    int sub = threadIdx.x >> 5;
    int i = threadIdx.x & 31;
    bf16_t* row = (grp < 4) ? (Qh + ((size_t)s * NH + grp * 4 + sub) * HD)
                            : (Kh + ((size_t)s * NKV + sub) * HD);
    float x0 = (float)row[2 * i];
    float x1 = (float)row[2 * i + 1];
    float p0 = (float)row[64 + 2 * i];
    float p1 = (float)row[64 + 2 * i + 1];
    float c0 = cosb[s * HD + 2 * i];
    float c1 = cosb[s * HD + 2 * i + 1];
    float n0 = sinb[s * HD + 2 * i];
    float n1 = sinb[s * HD + 2 * i + 1];
    float r0 = -x1, r1 = x0;
    row[2 * i]          = (bf16_t)(r0 * c0 + p0 * n0);
    row[2 * i + 1]      = (bf16_t)(r1 * c1 + p1 * n1);
    row[64 + 2 * i]     = (bf16_t)(-r0 * n0 + p0 * c0);
    row[64 + 2 * i + 1] = (bf16_t)(-r1 * n1 + p1 * c1);
}

// ---------------------------------------------------------------------------
// Flash attention v8: 512 threads = 8 waves -> 2 WAVES PER SIMD (latency
// hiding within the block; R11's 4-wave/1-per-SIMD version ran a fully
// exposed serial chain: MfmaUtil+VALU+LDS ~35% busy, 65% stall).
// Wave w: 16 q-rows (w&3) x 2 heads (w>>2). Same verified dataflow:
// swapped-operand QK, packed b64 P writes (wave-private sP), dbuf K/V tiles
// (one barrier/iter), interior tiles skip the causal compare, unnormalized
// partials + deferred combine. Grid (32, NKV, 2) = 256 blocks, split-2.
// ---------------------------------------------------------------------------
__global__ __launch_bounds__(512, 1) void flash_attn8(
    const bf16_t* __restrict__ Q,   // S x (NH*HD)
    const bf16_t* __restrict__ Kb,  // S x (NKV*HD)
    const bf16_t* __restrict__ VT,  // (NKV*HD) x S
    bf16_t* __restrict__ Opart,     // 2 x S x (NH*HD), unnormalized
    float* __restrict__ lpart,      // 2 x S x NH
    int S)
{
    __shared__ __align__(16) bf16_t sK[2][64 * 136];   // 34.8 KB
    __shared__ __align__(16) bf16_t sVT[2][128 * 72];  // 36.9 KB
    __shared__ __align__(16) bf16_t sP[8][16 * 72];    // 18.4 KB, wave-private

    const int qt  = blockIdx.x;
    const int kvh = blockIdx.y;
    const int z   = blockIdx.z;
    const int q0  = qt * 64;
    const int tid = threadIdx.x, lane = tid & 63, wave = tid >> 6;
    const int l16 = lane & 15, quad = lane >> 4;
    const int rowg = wave & 3;          // q-row group
    const int h0   = kvh * 4 + (wave >> 2) * 2;   // this wave's 2 heads
    const float scale = 0.08838834764831845f;     // 1/sqrt(128)

    const int nkt = qt + 1;
    const int hc  = nkt >> 1;
    const int tb  = z ? hc : 0;
    const int te  = z ? nkt : hc;

    const int qrow = q0 + rowg * 16 + l16;

    // Q fragments: 2 heads (B-operand of swapped QK)
    bf16x8 qf[2][4];
#pragma unroll
    for (int h = 0; h < 2; h++)
#pragma unroll
        for (int c = 0; c < 4; c++)
            qf[h][c] = *(const bf16x8*)&Q[(size_t)qrow * HID + (h0 + h) * HD + c * 32 + quad * 8];

    f32x4 oacc[2][8] = {};
    float lsum[2] = {0.f, 0.f};

    // staging: 1024 16B-chunks per tile, 512 threads -> 2 chunks each
    int krow[2], kcol[2], vrow[2], vcol[2];
#pragma unroll
    for (int it = 0; it < 2; it++) {
        int c = tid + 512 * it;
        krow[it] = c >> 4; kcol[it] = (c & 15) * 8;
        vrow[it] = c >> 3; vcol[it] = (c & 7) * 8;
    }

    // prologue: tile tb -> regs -> buf0; prefetch tb+1 into regs
    bf16x8 kpre[2], vpre[2];
#pragma unroll
    for (int it = 0; it < 2; it++) {
        kpre[it] = *(const bf16x8*)&Kb[(size_t)(tb * 64 + krow[it]) * (NKV * HD) + kvh * HD + kcol[it]];
        vpre[it] = *(const bf16x8*)&VT[((size_t)kvh * HD + vrow[it]) * S + tb * 64 + vcol[it]];
    }
#pragma unroll
    for (int it = 0; it < 2; it++) {
        *(bf16x8*)&sK[0][krow[it] * 136 + kcol[it]] = kpre[it];
        *(bf16x8*)&sVT[0][vrow[it] * 72 + vcol[it]] = vpre[it];
    }
    if (tb + 1 < te) {
        const int t1 = (tb + 1) * 64;
#pragma unroll
        for (int it = 0; it < 2; it++) {
            kpre[it] = *(const bf16x8*)&Kb[(size_t)(t1 + krow[it]) * (NKV * HD) + kvh * HD + kcol[it]];
            vpre[it] = *(const bf16x8*)&VT[((size_t)kvh * HD + vrow[it]) * S + t1 + vcol[it]];
        }
    }
    __syncthreads();

    int sel = 0;
    for (int kt = tb; kt < te; kt++) {
        const int t0 = kt * 64;
        const int ns = sel ^ 1;

        // stage tile kt+1 into the other buffer (overlaps compute)
        if (kt + 1 < te) {
#pragma unroll
            for (int it = 0; it < 2; it++) {
                *(bf16x8*)&sK[ns][krow[it] * 136 + kcol[it]] = kpre[it];
                *(bf16x8*)&sVT[ns][vrow[it] * 72 + vcol[it]] = vpre[it];
            }
            if (kt + 2 < te) {
                const int t2 = t0 + 128;
#pragma unroll
                for (int it = 0; it < 2; it++) {
                    kpre[it] = *(const bf16x8*)&Kb[(size_t)(t2 + krow[it]) * (NKV * HD) + kvh * HD + kcol[it]];
                    vpre[it] = *(const bf16x8*)&VT[((size_t)kvh * HD + vrow[it]) * S + t2 + vcol[it]];
                }
            }
        }

        // ---- QK^T (swapped): nt outer, kf read once, 2 heads share it ----
        f32x4 sc[2][4];   // [h][nt]
#pragma unroll
        for (int nt = 0; nt < 4; nt++) {
            bf16x8 kf[4];
#pragma unroll
            for (int c = 0; c < 4; c++)
                kf[c] = *(bf16x8*)&sK[sel][(nt * 16 + l16) * 136 + c * 32 + quad * 8];
#pragma unroll
            for (int h = 0; h < 2; h++) {
                f32x4 d = {};
#pragma unroll
                for (int c = 0; c < 4; c++)
                    d = __builtin_amdgcn_mfma_f32_16x16x32_bf16(kf[c], qf[h][c], d, 0, 0, 0);
                sc[h][nt] = d;
            }
        }

        // ---- exp + packed P write + A-frag read (wave-private sP) ----
        bf16x8 pa[2][2];
        if (kt == qt) {
#pragma unroll
            for (int h = 0; h < 2; h++) {
#pragma unroll
                for (int nt = 0; nt < 4; nt++) {
                    const int tbk = t0 + nt * 16 + quad * 4;
                    bf16x4 pk;
#pragma unroll
                    for (int r = 0; r < 4; r++) {
                        float p = (tbk + r <= qrow) ? __expf(sc[h][nt][r] * scale) : 0.0f;
                        lsum[h] += p;
                        pk[r] = (bf16_t)p;
                    }
                    *(bf16x4*)&sP[wave][l16 * 72 + nt * 16 + quad * 4] = pk;
                }
#pragma unroll
                for (int kc = 0; kc < 2; kc++)
                    pa[h][kc] = *(bf16x8*)&sP[wave][l16 * 72 + kc * 32 + quad * 8];
            }
        } else {
#pragma unroll
            for (int h = 0; h < 2; h++) {
#pragma unroll
                for (int nt = 0; nt < 4; nt++) {
                    bf16x4 pk;
#pragma unroll
                    for (int r = 0; r < 4; r++) {
                        float p = __expf(sc[h][nt][r] * scale);
                        lsum[h] += p;
                        pk[r] = (bf16_t)p;
                    }
                    *(bf16x4*)&sP[wave][l16 * 72 + nt * 16 + quad * 4] = pk;
                }
#pragma unroll
                for (int kc = 0; kc < 2; kc++)
                    pa[h][kc] = *(bf16x8*)&sP[wave][l16 * 72 + kc * 32 + quad * 8];
            }
        }

        // ---- PV: dt outer, vf read once, 2 heads share it ----
#pragma unroll
        for (int dt = 0; dt < 8; dt++)
#pragma unroll
            for (int kc = 0; kc < 2; kc++) {
                bf16x8 vf = *(bf16x8*)&sVT[sel][(dt * 16 + l16) * 72 + kc * 32 + quad * 8];
#pragma unroll
                for (int h = 0; h < 2; h++)
                    oacc[h][dt] = __builtin_amdgcn_mfma_f32_16x16x32_bf16(pa[h][kc], vf, oacc[h][dt], 0, 0, 0);
            }

        __syncthreads();   // buf[ns] writes visible; buf[sel] reads done
        sel = ns;
    }

    // epilogue: store UNNORMALIZED partial O + partial l
    bf16_t* Op = Opart + (size_t)z * S * HID;
#pragma unroll
    for (int h = 0; h < 2; h++) {
        float lr = lsum[h];
        lr += __shfl_xor(lr, 16, 64);
        lr += __shfl_xor(lr, 32, 64);   // lane L: l for row offset L&15
        if (quad == 0)
            lpart[((size_t)z * S + q0 + rowg * 16 + l16) * NH + (h0 + h)] = lr;
#pragma unroll
        for (int r = 0; r < 4; r++) {
            int srow = q0 + rowg * 16 + quad * 4 + r;
#pragma unroll
            for (int dt = 0; dt < 8; dt++)
                Op[(size_t)srow * HID + (h0 + h) * HD + dt * 16 + l16] =
                    (bf16_t)(oacc[h][dt][r]);
        }
    }
}

// ---------------------------------------------------------------------------
// Combine: oh = (O0 + O1) / (l0 + l1). 8 elems/thread (within one head).
// ---------------------------------------------------------------------------
__global__ __launch_bounds__(256) void flash_combine(
    const bf16_t* __restrict__ Opart, const float* __restrict__ lpart,
    bf16_t* __restrict__ oh)
{
    int i = (blockIdx.x * 256 + threadIdx.x) * 8;
    int s = i >> 11;            // row (2048 cols)
    int h = (i >> 7) & 15;      // head
    float l = lpart[(size_t)s * NH + h] + lpart[((size_t)S_LEN + s) * NH + h];
    float inv = 1.0f / l;
    bf16x8 a = *(const bf16x8*)&Opart[i];
    bf16x8 b = *(const bf16x8*)&Opart[(size_t)S_LEN * HID + i];
    bf16x8 o;
#pragma unroll
    for (int j = 0; j < 8; j++)
        o[j] = (bf16_t)(((float)a[j] + (float)b[j]) * inv);
    *(bf16x8*)&oh[i] = o;
}

// ---------------------------------------------------------------------------
extern "C" void kernel_launch(void* const* d_in, const int* in_sizes, int n_in,
                              void* d_out, int out_size, void* d_ws, size_t ws_size,
                              hipStream_t stream)
{
    const float* x    = (const float*)d_in[0];
    const float* cosb = (const float*)d_in[1];
    const float* sinb = (const float*)d_in[2];
    const float* wq   = (const float*)d_in[3];
    const float* wk   = (const float*)d_in[4];
    const float* wv   = (const float*)d_in[5];
    const float* wo   = (const float*)d_in[6];
    float* out = (float*)d_out;

    // Workspace (24.25 MB):
    char* ws = (char*)d_ws;
    bf16_t* wb = (bf16_t*)(ws);                              // 0..12 MB: [wq;wk;wv] bf16 (reused for wo)
    bf16_t* qh = (bf16_t*)(ws + (size_t)12 * 1024 * 1024);   // 12..20 MB: q / attn-out
    bf16_t* kh = (bf16_t*)(ws + (size_t)20 * 1024 * 1024);   // 20..22 MB: k
    bf16_t* vT = (bf16_t*)(ws + (size_t)22 * 1024 * 1024);   // 22..24 MB: v^T
    float*  lp = (float*) (ws + (size_t)24 * 1024 * 1024);   // 24..24.25 MB: partial l
    // d_out (16 MB) doubles as scratch: x bf16 (steps 1-3), then O partials.
    bf16_t* xb = (bf16_t*)d_out;
    bf16_t* op = (bf16_t*)d_out;   // 2 x 8 MB bf16 partial O

    const int NX = S_LEN * HID;   // 4 Mi

    // 1) x -> bf16 (into d_out scratch)
    cvt_f32_bf16<<<NX / (256 * 8), 256, 0, stream>>>(x, xb, NX);

    // 2) weights -> bf16
    cvt_w3<<<6 * 1024 * 1024 / (256 * 8), 256, 0, stream>>>(wq, wk, wv, wb);

    // 3) fused QKV GEMM (all-bf16, m97 recipe), routed outputs. grid 24x16.
    gemm128<1, bf16_t><<<dim3(24, 16), 256, 0, stream>>>(xb, wb, qh, kh, vT, 3072, HID);

    // 4) RoPE on q + k
    rope_all<<<dim3(S_LEN, 5), 128, 0, stream>>>(qh, kh, cosb, sinb);

    // 5) flash attention v8 (512 thr, 2 waves/SIMD), split-2 -> partials
    flash_attn8<<<dim3(32, NKV, 2), 512, 0, stream>>>(qh, kh, vT, op, lp, S_LEN);

    // 6) combine partials -> qh (attn output, normalized bf16)
    flash_combine<<<NX / (256 * 8), 256, 0, stream>>>(op, lp, qh);

    // 7) wo -> bf16 (reuses wb)
    cvt_f32_bf16<<<NX / (256 * 8), 256, 0, stream>>>(wo, wb, NX);

    // 8) out = attn_out @ wo^T -> fp32 d_out (overwrites partials). grid 16x16.
    gemm128<0, float><<<dim3(16, 16), 256, 0, stream>>>(qh, wb, out, nullptr, nullptr, HID, HID);
}